// Round 4
// baseline (1059.731 us; speedup 1.0000x reference)
//
#include <hip/hip_runtime.h>
#include <math.h>

#define NPTS 8192
#define KNB  16
#define C1   64
#define C2   128
#define NEG  0.2f
#define VEPS 1e-6f
#define NCH  32
#define CHSZ (NPTS/NCH)   // 256

// ======================= Morton reorder (exact permutation) =======================
__device__ __forceinline__ unsigned long long expand10(unsigned v) {
    unsigned long long r = v & 0x3FFu;
    r = (r | (r << 16)) & 0x030000FFULL;
    r = (r | (r <<  8)) & 0x0300F00FULL;
    r = (r | (r <<  4)) & 0x030C30C3ULL;
    r = (r | (r <<  2)) & 0x09249249ULL;
    return r;
}

__global__ __launch_bounds__(256) void keys_kernel(const float* __restrict__ x,
                                                   unsigned long long* __restrict__ keys)
{
    const int i = blockIdx.x * 256 + threadIdx.x;
    auto cell = [](float v) -> unsigned {
        float t = (v + 6.f) * (1024.f / 12.f);
        int c = (int)t;
        c = c < 0 ? 0 : (c > 1023 ? 1023 : c);
        return (unsigned)c;
    };
    const unsigned long long m = expand10(cell(x[3*i+0]))
                               | (expand10(cell(x[3*i+1])) << 1)
                               | (expand10(cell(x[3*i+2])) << 2);
    keys[i] = (m << 13) | (unsigned long long)i;   // unique keys -> total order
}

__global__ __launch_bounds__(256) void rank_kernel(const unsigned long long* __restrict__ keys,
                                                   const float* __restrict__ x,
                                                   float* __restrict__ xp,
                                                   int* __restrict__ perm)
{
    __shared__ unsigned long long sk[NPTS];   // 64 KB
    for (int j = threadIdx.x; j < NPTS; j += 256) sk[j] = keys[j];
    __syncthreads();
    const int i = blockIdx.x * 256 + threadIdx.x;
    const unsigned long long mine = sk[i];
    int r = 0;
    for (int j = 0; j < NPTS; j += 4)
        r += (int)(sk[j] < mine) + (int)(sk[j+1] < mine)
           + (int)(sk[j+2] < mine) + (int)(sk[j+3] < mine);
    perm[r] = i;
    xp[3*r+0] = x[3*i+0]; xp[3*r+1] = x[3*i+1]; xp[3*r+2] = x[3*i+2];
}

// ======================= KNN phase 1: per-chunk top-16 =======================
__global__ __launch_bounds__(256) void knn_part(const float* __restrict__ x,
                                                unsigned long long* __restrict__ parts)
{
    __shared__ __align__(16) float4 cpt[CHSZ];
    __shared__ unsigned long long sbuf[256 * 8];

    const int tid   = threadIdx.x;
    const int chunk = blockIdx.x & (NCH - 1);
    const int qg    = blockIdx.x >> 5;
    const int j0    = chunk * CHSZ;

    cpt[tid] = make_float4(x[3*(j0+tid)+0], x[3*(j0+tid)+1], x[3*(j0+tid)+2], 0.f);
    const int q = qg * 256 + tid;
    const float qx = x[3*q+0], qy = x[3*q+1], qz = x[3*q+2];
    __syncthreads();

    unsigned long long bd[16];
#pragma unroll
    for (int r = 0; r < 16; ++r) bd[r] = ~0ull;
    int cnt = 0;
    unsigned long long* mybuf = sbuf + tid * 8;

    auto flush = [&]() {
#pragma unroll
        for (int s = 0; s < 8; ++s) {
            if (s < cnt) {
                const unsigned long long k = mybuf[s];
                if (k < bd[15]) {
#pragma unroll
                    for (int p2 = 15; p2 > 0; --p2) {
                        const bool sh = k < bd[p2-1];
                        const bool pl = k < bd[p2];
                        bd[p2] = sh ? bd[p2-1] : (pl ? k : bd[p2]);
                    }
                    if (k < bd[0]) bd[0] = k;
                }
            }
        }
        cnt = 0;
    };

    for (int jj = 0; jj < CHSZ; ++jj) {
        const float4 p = cpt[jj];
        const float dx = qx - p.x, dy = qy - p.y, dz = qz - p.z;
        const double ddx = (double)dx, ddy = (double)dy, ddz = (double)dz;
        const double d2 = ddx*ddx + ddy*ddy + ddz*ddz;
        const unsigned long long key =
            (((unsigned long long)__double_as_longlong(d2)) & ~8191ull)
            | (unsigned long long)(j0 + jj);
        if (key < bd[15]) { mybuf[cnt] = key; ++cnt; }
        if (__any(cnt >= 8)) flush();
    }
    flush();

#pragma unroll
    for (int r = 0; r < 16; ++r)
        parts[((size_t)chunk * KNB + r) * NPTS + q] = bd[r];
}

// ======================= KNN phase 2: 32-way sorted merge =======================
__global__ __launch_bounds__(256) void knn_merge(const unsigned long long* __restrict__ parts,
                                                 int* __restrict__ idx_out)
{
    __shared__ unsigned char heads[256][NCH];
    const int tid = threadIdx.x;
    const int q = blockIdx.x * 256 + tid;
    unsigned char* h = heads[tid];
#pragma unroll
    for (int c = 0; c < NCH; ++c) h[c] = 0;
    for (int r = 0; r < KNB; ++r) {
        unsigned long long best = ~0ull; int bc = 0;
#pragma unroll
        for (int c = 0; c < NCH; ++c) {
            const unsigned long long k = parts[((size_t)c * KNB + h[c]) * NPTS + q];
            if (k < best) { best = k; bc = c; }
        }
        h[bc]++;
        idx_out[q*KNB + r] = (int)(best & 8191ull);
    }
}

// ======================= 4x4 register-tile GEMM (A in LDS, B global/L1) ========
#define FMA4(ar, b0, b1, b2, b3, acc) \
    acc.x = fmaf(ar.x,b0.x, fmaf(ar.y,b1.x, fmaf(ar.z,b2.x, fmaf(ar.w,b3.x, acc.x)))); \
    acc.y = fmaf(ar.x,b0.y, fmaf(ar.y,b1.y, fmaf(ar.z,b2.y, fmaf(ar.w,b3.y, acc.y)))); \
    acc.z = fmaf(ar.x,b0.z, fmaf(ar.y,b1.z, fmaf(ar.z,b2.z, fmaf(ar.w,b3.z, acc.z)))); \
    acc.w = fmaf(ar.x,b0.w, fmaf(ar.y,b1.w, fmaf(ar.z,b2.w, fmaf(ar.w,b3.w, acc.w))));

template<int W, int SA>
__device__ __forceinline__ void tile_gemm44(const float* __restrict__ A,
                                            const float* __restrict__ B,
                                            float* __restrict__ Cc,
                                            int TP, int tid, int nt)
{
    constexpr int DQ = W / 4;
    const int nunits = (TP >> 2) * DQ;
    for (int u = tid; u < nunits; u += nt) {
        const int tg = u / DQ;
        const int d  = (u - tg * DQ) * 4;
        const float* a0p = A + (tg*4+0)*SA;
        const float* a1p = A + (tg*4+1)*SA;
        const float* a2p = A + (tg*4+2)*SA;
        const float* a3p = A + (tg*4+3)*SA;
        float4 acc0 = {0,0,0,0}, acc1 = acc0, acc2 = acc0, acc3 = acc0;
        for (int c = 0; c < W; c += 4) {
            const float4 a0 = *reinterpret_cast<const float4*>(a0p + c);
            const float4 a1 = *reinterpret_cast<const float4*>(a1p + c);
            const float4 a2 = *reinterpret_cast<const float4*>(a2p + c);
            const float4 a3 = *reinterpret_cast<const float4*>(a3p + c);
            const float4 b0 = *reinterpret_cast<const float4*>(B + (c+0)*W + d);
            const float4 b1 = *reinterpret_cast<const float4*>(B + (c+1)*W + d);
            const float4 b2 = *reinterpret_cast<const float4*>(B + (c+2)*W + d);
            const float4 b3 = *reinterpret_cast<const float4*>(B + (c+3)*W + d);
            FMA4(a0, b0, b1, b2, b3, acc0);
            FMA4(a1, b0, b1, b2, b3, acc1);
            FMA4(a2, b0, b1, b2, b3, acc2);
            FMA4(a3, b0, b1, b2, b3, acc3);
        }
        *reinterpret_cast<float4*>(Cc + (tg*4+0)*SA + d) = acc0;
        *reinterpret_cast<float4*>(Cc + (tg*4+1)*SA + d) = acc1;
        *reinterpret_cast<float4*>(Cc + (tg*4+2)*SA + d) = acc2;
        *reinterpret_cast<float4*>(Cc + (tg*4+3)*SA + d) = acc3;
    }
}

// ======================= W-hoisted Kronecker step =======================
template<int PIN, int NTH, bool FIRST, bool LAST>
__global__ __launch_bounds__(NTH) void kron2(const float* __restrict__ x,
                                             const int* __restrict__ idxs,
                                             const float* __restrict__ yin,
                                             const float* __restrict__ Wfirst,
                                             const float* __restrict__ Um,
                                             const float* __restrict__ Wnext,
                                             float* __restrict__ yout,
                                             const float* __restrict__ w4,
                                             float* __restrict__ hv,
                                             float* __restrict__ gpart,
                                             int ppb)
{
    constexpr int T  = 3 * PIN;
    constexpr int TP = (T + 3) & ~3;
    constexpr int SA = C1 + 4;
    constexpr int TC = T * C1;
    constexpr int PC = PIN * C1;
    constexpr int G4 = NTH / 64;
    constexpr int NG = LAST ? (TC + NTH - 1) / NTH : 1;

    __shared__ __align__(16) float bufV[TP*SA];
    __shared__ __align__(16) float bufD[TP*SA];
    __shared__ float xg[KNB*3];
    __shared__ int   ids[KNB];
    __shared__ float dotc[C1], psc[C1];
    __shared__ float pdt[G4][C1], pdn[G4][C1];
    __shared__ float mx[4];
    __shared__ float Scol[FIRST ? C1 : 4];

    const int tid = threadIdx.x;
    const int nt  = NTH;

    // XCD-aware swizzle: each XCD owns a contiguous Morton range (grid % 8 == 0)
    const int cpx = gridDim.x >> 3;
    const int eff = (blockIdx.x & 7) * cpx + (blockIdx.x >> 3);

    if (FIRST && tid < C1) {
        float s = 0.f;
        for (int j = 0; j < C1; ++j) s += Wfirst[j*C1 + tid];
        Scol[tid] = s;
    }
    for (int e = tid; e < (TP - T) * C1; e += nt)
        bufV[(T + (e >> 6))*SA + (e & 63)] = 0.f;
    float gacc[NG];
#pragma unroll
    for (int i = 0; i < NG; ++i) gacc[i] = 0.f;
    __syncthreads();

    const int p0 = eff * ppb;
    for (int pi = 0; pi < ppb; ++pi) {
        const int pt = p0 + pi;
        if (tid < KNB) ids[tid] = idxs[pt*KNB + tid];
        if (tid >= 64 && tid < 64 + KNB*3) {
            const int t2 = tid - 64, k = t2 / 3, a = t2 - 3*k;
            xg[t2] = x[3*idxs[pt*KNB + k] + a];
        }
        __syncthreads();

        if (FIRST) {
            if (tid < 3) {
                float s = 0.f;
                for (int k = 0; k < KNB; ++k) s += xg[k*3 + tid];
                mx[tid] = s * (1.0f/KNB);
            }
            __syncthreads();
            for (int e = tid; e < TC; e += nt)
                bufV[(e >> 6)*SA + (e & 63)] = mx[e >> 6] * Scol[e & 63];
        } else {
            for (int e4 = tid * 4; e4 < PC; e4 += nt * 4) {
                float4 s0 = {0,0,0,0}, s1 = {0,0,0,0}, s2 = {0,0,0,0};
#pragma unroll
                for (int k = 0; k < KNB; ++k) {
                    const float4 val = *reinterpret_cast<const float4*>(yin + (size_t)ids[k]*PC + e4);
                    const float xa = xg[k*3+0], xb = xg[k*3+1], xc = xg[k*3+2];
                    s0.x = fmaf(xa, val.x, s0.x); s0.y = fmaf(xa, val.y, s0.y);
                    s0.z = fmaf(xa, val.z, s0.z); s0.w = fmaf(xa, val.w, s0.w);
                    s1.x = fmaf(xb, val.x, s1.x); s1.y = fmaf(xb, val.y, s1.y);
                    s1.z = fmaf(xb, val.z, s1.z); s1.w = fmaf(xb, val.w, s1.w);
                    s2.x = fmaf(xc, val.x, s2.x); s2.y = fmaf(xc, val.y, s2.y);
                    s2.z = fmaf(xc, val.z, s2.z); s2.w = fmaf(xc, val.w, s2.w);
                }
                const float inv = 1.0f / KNB;
                s0.x*=inv; s0.y*=inv; s0.z*=inv; s0.w*=inv;
                s1.x*=inv; s1.y*=inv; s1.z*=inv; s1.w*=inv;
                s2.x*=inv; s2.y*=inv; s2.z*=inv; s2.w*=inv;
                const int b = e4 >> 6, c = e4 & 63;
                *reinterpret_cast<float4*>(bufV + (0*PIN + b)*SA + c) = s0;
                *reinterpret_cast<float4*>(bufV + (1*PIN + b)*SA + c) = s1;
                *reinterpret_cast<float4*>(bufV + (2*PIN + b)*SA + c) = s2;
            }
        }
        __syncthreads();
        tile_gemm44<C1, SA>(bufV, Um, bufD, TP, tid, nt);   // d = v @ U (B from L1/L2)
        __syncthreads();
        {
            const int c = tid & 63, g4 = tid >> 6;
            float dt = 0.f, dn = 0.f;
            for (int t = g4; t < T; t += G4) {
                const float vv = bufV[t*SA + c], dd = bufD[t*SA + c];
                dt = fmaf(vv, dd, dt); dn = fmaf(dd, dd, dn);
            }
            pdt[g4][c] = dt; pdn[g4][c] = dn;
        }
        __syncthreads();
        if (tid < C1) {
            float dt = 0.f, dn = 0.f;
#pragma unroll
            for (int g4 = 0; g4 < G4; ++g4) { dt += pdt[g4][tid]; dn += pdn[g4][tid]; }
            dotc[tid] = dt; psc[tid] = dt / (dn + VEPS);
        }
        __syncthreads();
        for (int e = tid; e < TC; e += nt) {
            const int t = e >> 6, c = e & 63;
            const float vv = bufV[t*SA + c], dd = bufD[t*SA + c];
            const float rr = (dotc[c] >= 0.f) ? vv : fmaf(-psc[c], dd, vv);
            bufV[t*SA + c] = NEG*vv + (1.f-NEG)*rr;
        }
        __syncthreads();
        if (!LAST) {
            for (int u = tid; u < (TP >> 2) * 16; u += nt) {
                const int tg = u >> 4;
                const int d  = (u & 15) * 4;
                const float* a0p = bufV + (tg*4+0)*SA;
                const float* a1p = bufV + (tg*4+1)*SA;
                const float* a2p = bufV + (tg*4+2)*SA;
                const float* a3p = bufV + (tg*4+3)*SA;
                float4 acc0 = {0,0,0,0}, acc1 = acc0, acc2 = acc0, acc3 = acc0;
                for (int c = 0; c < C1; c += 4) {
                    const float4 a0 = *reinterpret_cast<const float4*>(a0p + c);
                    const float4 a1 = *reinterpret_cast<const float4*>(a1p + c);
                    const float4 a2 = *reinterpret_cast<const float4*>(a2p + c);
                    const float4 a3 = *reinterpret_cast<const float4*>(a3p + c);
                    const float4 b0 = *reinterpret_cast<const float4*>(Wnext + (c+0)*C1 + d);
                    const float4 b1 = *reinterpret_cast<const float4*>(Wnext + (c+1)*C1 + d);
                    const float4 b2 = *reinterpret_cast<const float4*>(Wnext + (c+2)*C1 + d);
                    const float4 b3 = *reinterpret_cast<const float4*>(Wnext + (c+3)*C1 + d);
                    FMA4(a0, b0, b1, b2, b3, acc0);
                    FMA4(a1, b0, b1, b2, b3, acc1);
                    FMA4(a2, b0, b1, b2, b3, acc2);
                    FMA4(a3, b0, b1, b2, b3, acc3);
                }
                float* op = yout + (size_t)pt * TC;
                if (tg*4+0 < T) *reinterpret_cast<float4*>(op + (tg*4+0)*C1 + d) = acc0;
                if (tg*4+1 < T) *reinterpret_cast<float4*>(op + (tg*4+1)*C1 + d) = acc1;
                if (tg*4+2 < T) *reinterpret_cast<float4*>(op + (tg*4+2)*C1 + d) = acc2;
                if (tg*4+3 < T) *reinterpret_cast<float4*>(op + (tg*4+3)*C1 + d) = acc3;
            }
        } else {
#pragma unroll
            for (int i = 0; i < NG; ++i) {
                const int e = i*NTH + tid;
                if (e < TC) gacc[i] += bufV[(e >> 6)*SA + (e & 63)];
            }
            for (int e = tid; e < 9*C1; e += nt) {
                const int pq = e >> 6, c = e & 63;
                const int p = pq / 3, qq = pq - 3*p;
                float tr0=0,tr1=0,tr2=0,tr3=0,tr4=0,tr5=0;
#pragma unroll
                for (int r = 0; r < 3; ++r) {
                    tr0 += bufV[(r*36 + p*3 + qq )*SA + c];
                    tr1 += bufV[(r*30 + p*9 + qq )*SA + c];
                    tr2 += bufV[(r*28 + p*9 + qq*3)*SA + c];
                    tr3 += bufV[(p*27 + r*12 + qq )*SA + c];
                    tr4 += bufV[(p*27 + r*10 + qq*3)*SA + c];
                    tr5 += bufV[(p*27 + qq*9 + r*4 )*SA + c];
                }
                const float acc = w4[0*C2 + c]*tr0 + w4[1*C2 + c]*tr1 + w4[2*C2 + c]*tr2
                                + w4[3*C2 + c]*tr3 + w4[4*C2 + c]*tr4 + w4[5*C2 + c]*tr5;
                hv[(size_t)pt * (9*C1) + e] = acc;
            }
        }
        __syncthreads();
    }
    if (LAST) {
#pragma unroll
        for (int i = 0; i < NG; ++i) {
            const int e = i*NTH + tid;
            if (e < TC) gpart[(size_t)eff * TC + e] = gacc[i];
        }
    }
}

// ======================= g reduction =======================
__global__ __launch_bounds__(256) void reduce_g_kernel(const float* __restrict__ gpart,
                                                       float* __restrict__ g)
{
    __shared__ float red[256];
    const int el = threadIdx.x & 15, pg = threadIdx.x >> 4;
    const int e = blockIdx.x * 16 + el;
    float s = 0.f;
    for (int p = pg; p < 512; p += 16) s += gpart[(size_t)p * (81*C1) + e];
    red[threadIdx.x] = s;
    __syncthreads();
    for (int st = 8; st > 0; st >>= 1) {
        if (pg < st) red[el + 16*pg] += red[el + 16*(pg+st)];
        __syncthreads();
    }
    if (pg == 0) g[e] = red[el] * (1.0f/NPTS);
}

// ======================= hg + hgW precompute =======================
__global__ __launch_bounds__(256) void hgw_kernel(const float* __restrict__ g,
                                                  const float* __restrict__ w4,
                                                  const float* __restrict__ cW,
                                                  float* __restrict__ hgW)
{
    __shared__ float gs[81*C1];
    __shared__ float hg[9*C1];
    const int tid = threadIdx.x;
    for (int e = tid; e < 81*C1; e += 256) gs[e] = g[e];
    __syncthreads();
    for (int e = tid; e < 9*C1; e += 256) {
        const int pq = e >> 6, c = e & 63;
        const int p = pq / 3, qq = pq - 3*p;
        float tr0=0,tr1=0,tr2=0,tr3=0,tr4=0,tr5=0;
#pragma unroll
        for (int r = 0; r < 3; ++r) {
            tr0 += gs[(r*36 + p*3 + qq ) * C1 + c];
            tr1 += gs[(r*30 + p*9 + qq ) * C1 + c];
            tr2 += gs[(r*28 + p*9 + qq*3) * C1 + c];
            tr3 += gs[(p*27 + r*12 + qq ) * C1 + c];
            tr4 += gs[(p*27 + r*10 + qq*3) * C1 + c];
            tr5 += gs[(p*27 + qq*9 + r*4 ) * C1 + c];
        }
        hg[e] = w4[0*C2 + 64 + c]*tr0 + w4[1*C2 + 64 + c]*tr1 + w4[2*C2 + 64 + c]*tr2
              + w4[3*C2 + 64 + c]*tr3 + w4[4*C2 + 64 + c]*tr4 + w4[5*C2 + 64 + c]*tr5;
    }
    __syncthreads();
    for (int o = tid; o < 9*C2; o += 256) {
        const int t = o >> 7, c = o & 127;
        float s = 0.f;
        for (int j = 0; j < C1; ++j) s = fmaf(hg[t*C1 + j], cW[(C1+j)*C2 + c], s);
        hgW[o] = s;
    }
}

// ======================= contraction head =======================
__global__ __launch_bounds__(256) void contract_kernel(const float* __restrict__ hv,
                                                       const float* __restrict__ hgW,
                                                       const float* __restrict__ cW,
                                                       const float* __restrict__ cU,
                                                       const float* __restrict__ w2,
                                                       const int* __restrict__ perm,
                                                       float* __restrict__ out,
                                                       int ppb)
{
    constexpr int S0 = C1 + 4;    // 68
    constexpr int SH = C2 + 4;    // 132
    __shared__ __align__(16) float h0[36*S0];
    __shared__ __align__(16) float h1[36*SH];
    __shared__ __align__(16) float h2[36*SH];
    __shared__ __align__(16) float hgs[9*C2];
    __shared__ int sPerm[4];

    const int tid = threadIdx.x;
    for (int e = tid; e < 9*C2; e += 256) hgs[e] = hgW[e];
    __syncthreads();

    const int iters = ppb >> 2;
    for (int it = 0; it < iters; ++it) {
        const int base = blockIdx.x * ppb + it * 4;
        if (tid < 4) sPerm[tid] = perm[base + tid];
        for (int e = tid; e < 4*9*C1; e += 256) {
            const int pt = e / 576, rem = e - pt*576;
            const int t = rem >> 6, c = rem & 63;
            h0[(pt*9 + t)*S0 + c] = hv[(size_t)(base+pt)*576 + rem];
        }
        __syncthreads();
        for (int u = tid; u < 9*32; u += 256) {
            const int tg = u >> 5;
            const int d  = (u & 31) * 4;
            const int r0 = tg*4;
            float4 acc0 = *reinterpret_cast<const float4*>(hgs + ((r0+0)%9)*C2 + d);
            float4 acc1 = *reinterpret_cast<const float4*>(hgs + ((r0+1)%9)*C2 + d);
            float4 acc2 = *reinterpret_cast<const float4*>(hgs + ((r0+2)%9)*C2 + d);
            float4 acc3 = *reinterpret_cast<const float4*>(hgs + ((r0+3)%9)*C2 + d);
            for (int c = 0; c < C1; c += 4) {
                const float4 a0 = *reinterpret_cast<const float4*>(h0 + (r0+0)*S0 + c);
                const float4 a1 = *reinterpret_cast<const float4*>(h0 + (r0+1)*S0 + c);
                const float4 a2 = *reinterpret_cast<const float4*>(h0 + (r0+2)*S0 + c);
                const float4 a3 = *reinterpret_cast<const float4*>(h0 + (r0+3)*S0 + c);
                const float4 b0 = *reinterpret_cast<const float4*>(cW + (c+0)*C2 + d);
                const float4 b1 = *reinterpret_cast<const float4*>(cW + (c+1)*C2 + d);
                const float4 b2 = *reinterpret_cast<const float4*>(cW + (c+2)*C2 + d);
                const float4 b3 = *reinterpret_cast<const float4*>(cW + (c+3)*C2 + d);
                FMA4(a0, b0, b1, b2, b3, acc0);
                FMA4(a1, b0, b1, b2, b3, acc1);
                FMA4(a2, b0, b1, b2, b3, acc2);
                FMA4(a3, b0, b1, b2, b3, acc3);
            }
            *reinterpret_cast<float4*>(h1 + (r0+0)*SH + d) = acc0;
            *reinterpret_cast<float4*>(h1 + (r0+1)*SH + d) = acc1;
            *reinterpret_cast<float4*>(h1 + (r0+2)*SH + d) = acc2;
            *reinterpret_cast<float4*>(h1 + (r0+3)*SH + d) = acc3;
        }
        __syncthreads();
        for (int u = tid; u < 9*32; u += 256) {
            const int tg = u >> 5;
            const int d  = (u & 31) * 4;
            const int r0 = tg*4;
            float4 acc0 = {0,0,0,0}, acc1 = acc0, acc2 = acc0, acc3 = acc0;
            for (int c = 0; c < C2; c += 4) {
                const float4 a0 = *reinterpret_cast<const float4*>(h1 + (r0+0)*SH + c);
                const float4 a1 = *reinterpret_cast<const float4*>(h1 + (r0+1)*SH + c);
                const float4 a2 = *reinterpret_cast<const float4*>(h1 + (r0+2)*SH + c);
                const float4 a3 = *reinterpret_cast<const float4*>(h1 + (r0+3)*SH + c);
                const float4 b0 = *reinterpret_cast<const float4*>(cU + (c+0)*C2 + d);
                const float4 b1 = *reinterpret_cast<const float4*>(cU + (c+1)*C2 + d);
                const float4 b2 = *reinterpret_cast<const float4*>(cU + (c+2)*C2 + d);
                const float4 b3 = *reinterpret_cast<const float4*>(cU + (c+3)*C2 + d);
                FMA4(a0, b0, b1, b2, b3, acc0);
                FMA4(a1, b0, b1, b2, b3, acc1);
                FMA4(a2, b0, b1, b2, b3, acc2);
                FMA4(a3, b0, b1, b2, b3, acc3);
            }
            *reinterpret_cast<float4*>(h2 + (r0+0)*SH + d) = acc0;
            *reinterpret_cast<float4*>(h2 + (r0+1)*SH + d) = acc1;
            *reinterpret_cast<float4*>(h2 + (r0+2)*SH + d) = acc2;
            *reinterpret_cast<float4*>(h2 + (r0+3)*SH + d) = acc3;
        }
        __syncthreads();
#pragma unroll
        for (int p2 = 0; p2 < 2; ++p2) {
            const int pair = tid + 256*p2;
            const int pt = pair >> 7, c = pair & 127;
            float dt = 0.f, dn = 0.f;
            for (int t = 0; t < 9; ++t) {
                const float vv = h1[(pt*9+t)*SH + c], dd = h2[(pt*9+t)*SH + c];
                dt = fmaf(vv, dd, dt); dn = fmaf(dd, dd, dn);
            }
            const float ps = dt / (dn + VEPS);
            float s = 0.f;
#pragma unroll
            for (int r = 0; r < 3; ++r) {
                const int t = r * 4;
                const float vv = h1[(pt*9+t)*SH + c], dd = h2[(pt*9+t)*SH + c];
                const float rr = (dt >= 0.f) ? vv : fmaf(-ps, dd, vv);
                s += NEG*vv + (1.f-NEG)*rr;
            }
            out[(size_t)sPerm[pt]*C2 + c] = w2[c] * s;
        }
        __syncthreads();
    }
}

// ======================= launcher =======================
extern "C" void kernel_launch(void* const* d_in, const int* in_sizes, int n_in,
                              void* d_out, int out_size, void* d_ws, size_t ws_size,
                              hipStream_t stream)
{
    (void)in_sizes; (void)n_in; (void)out_size; (void)ws_size;
    const float* x  = (const float*)d_in[0];
    const float* kW = (const float*)d_in[1];
    const float* kU = (const float*)d_in[2];
    const float* w4 = (const float*)d_in[3];
    const float* cW = (const float*)d_in[4];
    const float* cU = (const float*)d_in[5];
    const float* w2 = (const float*)d_in[6];
    float* out = (float*)d_out;

    char* ws = (char*)d_ws;
    size_t off = 0;
    auto alloc = [&](size_t bytes) -> void* {
        void* p = ws + off; off += (bytes + 255) & ~(size_t)255; return p;
    };
    int*   idx   = (int*)  alloc((size_t)NPTS*KNB*4);
    float* y1    = (float*)alloc((size_t)NPTS*3*C1*4);       // 6.3 MB
    float* y2    = (float*)alloc((size_t)NPTS*9*C1*4);       // 18.9 MB (hv alias)
    float* y3    = (float*)alloc((size_t)NPTS*27*C1*4);      // 56.6 MB (knn parts alias)
    float* gpart = (float*)alloc((size_t)512*81*C1*4);       // 10.6 MB
    float* g     = (float*)alloc((size_t)81*C1*4);
    float* hgW   = (float*)alloc((size_t)9*C2*4);
    unsigned long long* keys = (unsigned long long*)alloc((size_t)NPTS*8);
    float* xp    = (float*)alloc((size_t)NPTS*3*4);
    int*   perm  = (int*)  alloc((size_t)NPTS*4);
    float* hv    = y2;
    unsigned long long* parts = (unsigned long long*)y3;

    keys_kernel<<<NPTS/256, 256, 0, stream>>>(x, keys);
    rank_kernel<<<NPTS/256, 256, 0, stream>>>(keys, x, xp, perm);
    knn_part <<<1024, 256, 0, stream>>>(xp, parts);
    knn_merge<<<NPTS/256, 256, 0, stream>>>(parts, idx);
    kron2<1,  256, true,  false><<<1024, 256, 0, stream>>>(xp, idx, nullptr, kW, kU,       kW+4096,  y1, nullptr, nullptr, nullptr, 8);
    kron2<3,  256, false, false><<<1024, 256, 0, stream>>>(xp, idx, y1, nullptr, kU+4096,  kW+8192,  y2, nullptr, nullptr, nullptr, 8);
    kron2<9,  256, false, false><<<1024, 256, 0, stream>>>(xp, idx, y2, nullptr, kU+8192,  kW+12288, y3, nullptr, nullptr, nullptr, 8);
    kron2<27, 512, false, true ><<<512,  512, 0, stream>>>(xp, idx, y3, nullptr, kU+12288, nullptr,  nullptr, w4, hv, gpart, 16);
    reduce_g_kernel<<<324, 256, 0, stream>>>(gpart, g);
    hgw_kernel<<<1, 256, 0, stream>>>(g, w4, cW, hgW);
    contract_kernel<<<1024, 256, 0, stream>>>(hv, hgW, cW, cU, w2, perm, out, 8);
}

// Round 5
// 959.029 us; speedup vs baseline: 1.1050x; 1.1050x over previous
//
#include <hip/hip_runtime.h>
#include <math.h>

#define NPTS 8192
#define KNB  16
#define C1   64
#define C2   128
#define NEG  0.2f
#define VEPS 1e-6f
#define NCH  32
#define CHSZ (NPTS/NCH)   // 256

// ======================= Morton reorder (exact permutation) =======================
__device__ __forceinline__ unsigned long long expand10(unsigned v) {
    unsigned long long r = v & 0x3FFu;
    r = (r | (r << 16)) & 0x030000FFULL;
    r = (r | (r <<  8)) & 0x0300F00FULL;
    r = (r | (r <<  4)) & 0x030C30C3ULL;
    r = (r | (r <<  2)) & 0x09249249ULL;
    return r;
}

__global__ __launch_bounds__(256) void keys_kernel(const float* __restrict__ x,
                                                   unsigned long long* __restrict__ keys)
{
    const int i = blockIdx.x * 256 + threadIdx.x;
    auto cell = [](float v) -> unsigned {
        float t = (v + 6.f) * (1024.f / 12.f);
        int c = (int)t;
        c = c < 0 ? 0 : (c > 1023 ? 1023 : c);
        return (unsigned)c;
    };
    const unsigned long long m = expand10(cell(x[3*i+0]))
                               | (expand10(cell(x[3*i+1])) << 1)
                               | (expand10(cell(x[3*i+2])) << 2);
    keys[i] = (m << 13) | (unsigned long long)i;
}

__global__ __launch_bounds__(256) void rank_kernel(const unsigned long long* __restrict__ keys,
                                                   const float* __restrict__ x,
                                                   float* __restrict__ xp,
                                                   int* __restrict__ perm)
{
    __shared__ unsigned long long sk[NPTS];
    for (int j = threadIdx.x; j < NPTS; j += 256) sk[j] = keys[j];
    __syncthreads();
    const int i = blockIdx.x * 256 + threadIdx.x;
    const unsigned long long mine = sk[i];
    int r = 0;
    for (int j = 0; j < NPTS; j += 4)
        r += (int)(sk[j] < mine) + (int)(sk[j+1] < mine)
           + (int)(sk[j+2] < mine) + (int)(sk[j+3] < mine);
    perm[r] = i;
    xp[3*r+0] = x[3*i+0]; xp[3*r+1] = x[3*i+1]; xp[3*r+2] = x[3*i+2];
}

// ======================= KNN phase 1: per-chunk top-16 =======================
__global__ __launch_bounds__(256) void knn_part(const float* __restrict__ x,
                                                unsigned long long* __restrict__ parts)
{
    __shared__ __align__(16) float4 cpt[CHSZ];
    __shared__ unsigned long long sbuf[256 * 8];

    const int tid   = threadIdx.x;
    const int chunk = blockIdx.x & (NCH - 1);
    const int qg    = blockIdx.x >> 5;
    const int j0    = chunk * CHSZ;

    cpt[tid] = make_float4(x[3*(j0+tid)+0], x[3*(j0+tid)+1], x[3*(j0+tid)+2], 0.f);
    const int q = qg * 256 + tid;
    const float qx = x[3*q+0], qy = x[3*q+1], qz = x[3*q+2];
    __syncthreads();

    unsigned long long bd[16];
#pragma unroll
    for (int r = 0; r < 16; ++r) bd[r] = ~0ull;
    int cnt = 0;
    unsigned long long* mybuf = sbuf + tid * 8;

    auto flush = [&]() {
#pragma unroll
        for (int s = 0; s < 8; ++s) {
            if (s < cnt) {
                const unsigned long long k = mybuf[s];
                if (k < bd[15]) {
#pragma unroll
                    for (int p2 = 15; p2 > 0; --p2) {
                        const bool sh = k < bd[p2-1];
                        const bool pl = k < bd[p2];
                        bd[p2] = sh ? bd[p2-1] : (pl ? k : bd[p2]);
                    }
                    if (k < bd[0]) bd[0] = k;
                }
            }
        }
        cnt = 0;
    };

    for (int jj = 0; jj < CHSZ; ++jj) {
        const float4 p = cpt[jj];
        const float dx = qx - p.x, dy = qy - p.y, dz = qz - p.z;
        const double ddx = (double)dx, ddy = (double)dy, ddz = (double)dz;
        const double d2 = ddx*ddx + ddy*ddy + ddz*ddz;
        const unsigned long long key =
            (((unsigned long long)__double_as_longlong(d2)) & ~8191ull)
            | (unsigned long long)(j0 + jj);
        if (key < bd[15]) { mybuf[cnt] = key; ++cnt; }
        if (__any(cnt >= 8)) flush();
    }
    flush();

#pragma unroll
    for (int r = 0; r < 16; ++r)
        parts[((size_t)chunk * KNB + r) * NPTS + q] = bd[r];
}

// ======================= KNN phase 2: 32-way sorted merge =======================
__global__ __launch_bounds__(256) void knn_merge(const unsigned long long* __restrict__ parts,
                                                 int* __restrict__ idx_out)
{
    __shared__ unsigned char heads[256][NCH];
    const int tid = threadIdx.x;
    const int q = blockIdx.x * 256 + tid;
    unsigned char* h = heads[tid];
#pragma unroll
    for (int c = 0; c < NCH; ++c) h[c] = 0;
    for (int r = 0; r < KNB; ++r) {
        unsigned long long best = ~0ull; int bc = 0;
#pragma unroll
        for (int c = 0; c < NCH; ++c) {
            const unsigned long long k = parts[((size_t)c * KNB + h[c]) * NPTS + q];
            if (k < best) { best = k; bc = c; }
        }
        h[bc]++;
        idx_out[q*KNB + r] = (int)(best & 8191ull);
    }
}

// ======================= prep: Scol1/ScolU1 + Bcat_t = [W_t | W_t@U_t] ==========
__global__ __launch_bounds__(256) void prep_kernel(const float* __restrict__ kW,
                                                   const float* __restrict__ kU,
                                                   float* __restrict__ scol,
                                                   float* __restrict__ bcat)
{
    __shared__ float sW[64*64];
    __shared__ float sS[64];
    const int t = blockIdx.x;   // 0: scol pair for step1; 1..3: bcat for steps 2..4
    const int tid = threadIdx.x;
    if (t == 0) {
        for (int e = tid; e < 64*64; e += 256) sW[e] = kW[e];
        __syncthreads();
        if (tid < 64) {
            float s = 0.f;
            for (int j = 0; j < 64; ++j) s += sW[j*64 + tid];
            sS[tid] = s;
        }
        __syncthreads();
        if (tid < 64) {
            float s2 = 0.f;
            for (int j = 0; j < 64; ++j) s2 = fmaf(sS[j], kU[j*64 + tid], s2);
            scol[tid]      = sS[tid];
            scol[64 + tid] = s2;
        }
    } else {
        const float* W = kW + t*4096;
        const float* U = kU + t*4096;
        for (int e = tid; e < 64*64; e += 256) sW[e] = W[e];
        __syncthreads();
        float* B = bcat + (size_t)(t-1)*64*128;
        for (int o = tid; o < 64*64; o += 256) {
            const int j = o >> 6, c = o & 63;
            float s = 0.f;
            for (int l = 0; l < 64; ++l) s = fmaf(sW[j*64 + l], U[l*64 + c], s);
            B[j*128 + c]      = sW[j*64 + c];
            B[j*128 + 64 + c] = s;
        }
    }
}

// ======================= step1: rank-1 closed form =======================
// R1[a,c] = mx[a] * (Scol[c] - m_c * ScolU[c]);  m from dot = S2*Scol*ScolU.
__global__ __launch_bounds__(256) void step1_kernel(const float* __restrict__ xp,
                                                    const int* __restrict__ idxs,
                                                    const float* __restrict__ scol,
                                                    float* __restrict__ R1)
{
    const int pt = blockIdx.x * 256 + threadIdx.x;
    float mx0 = 0.f, mx1 = 0.f, mx2 = 0.f;
#pragma unroll
    for (int k = 0; k < KNB; ++k) {
        const int id = idxs[pt*KNB + k];
        mx0 += xp[3*id+0]; mx1 += xp[3*id+1]; mx2 += xp[3*id+2];
    }
    const float inv = 1.0f / KNB;
    mx0 *= inv; mx1 *= inv; mx2 *= inv;
    const float S2 = mx0*mx0 + mx1*mx1 + mx2*mx2;
    float* op = R1 + (size_t)pt * 192;
    for (int c = 0; c < 64; ++c) {
        const float sc = scol[c], su = scol[64 + c];
        const float dt = S2 * sc * su;
        const float dn = S2 * su * su;
        const float m  = (dt < 0.f) ? 0.8f * dt / (dn + VEPS) : 0.f;
        const float rc = fmaf(-m, su, sc);
        op[c]       = mx0 * rc;
        op[64 + c]  = mx1 * rc;
        op[128 + c] = mx2 * rc;
    }
}

// ======================= zgemm: YwZ = R @ Bcat (K=64, N=128) =======================
#define FMA4(ar, b0, b1, b2, b3, acc) \
    acc.x = fmaf(ar.x,b0.x, fmaf(ar.y,b1.x, fmaf(ar.z,b2.x, fmaf(ar.w,b3.x, acc.x)))); \
    acc.y = fmaf(ar.x,b0.y, fmaf(ar.y,b1.y, fmaf(ar.z,b2.y, fmaf(ar.w,b3.y, acc.y)))); \
    acc.z = fmaf(ar.x,b0.z, fmaf(ar.y,b1.z, fmaf(ar.z,b2.z, fmaf(ar.w,b3.z, acc.z)))); \
    acc.w = fmaf(ar.x,b0.w, fmaf(ar.y,b1.w, fmaf(ar.z,b2.w, fmaf(ar.w,b3.w, acc.w))));

// block: 64 rows; thread = (rowgroup of 8) x (4-col group of 32): 256 units exactly.
__global__ __launch_bounds__(256) void zgemm_kernel(const float* __restrict__ R,
                                                    const float* __restrict__ Bcat,
                                                    float* __restrict__ YwZ)
{
    constexpr int SA = 68;
    __shared__ __align__(16) float sA[64*SA];
    __shared__ __align__(16) float sB[64*128];
    const int tid = threadIdx.x;
    const size_t row0 = (size_t)blockIdx.x * 64;

    for (int e4 = tid; e4 < 1024; e4 += 256) {
        const int r = e4 >> 4, c4 = (e4 & 15) * 4;
        *reinterpret_cast<float4*>(sA + r*SA + c4) =
            *reinterpret_cast<const float4*>(R + (row0 + r)*64 + c4);
    }
    for (int e4 = tid; e4 < 2048; e4 += 256) {
        const int j = e4 >> 5, c4 = (e4 & 31) * 4;
        *reinterpret_cast<float4*>(sB + j*128 + c4) =
            *reinterpret_cast<const float4*>(Bcat + j*128 + c4);
    }
    __syncthreads();

    const int rg = tid >> 5;           // 0..7
    const int d  = (tid & 31) * 4;     // 0..124
    float4 acc0={0,0,0,0},acc1=acc0,acc2=acc0,acc3=acc0,acc4=acc0,acc5=acc0,acc6=acc0,acc7=acc0;
    for (int c = 0; c < 64; c += 4) {
        const float4 b0 = *reinterpret_cast<const float4*>(sB + (c+0)*128 + d);
        const float4 b1 = *reinterpret_cast<const float4*>(sB + (c+1)*128 + d);
        const float4 b2 = *reinterpret_cast<const float4*>(sB + (c+2)*128 + d);
        const float4 b3 = *reinterpret_cast<const float4*>(sB + (c+3)*128 + d);
        float4 a;
        a = *reinterpret_cast<const float4*>(sA + (rg*8+0)*SA + c); FMA4(a,b0,b1,b2,b3,acc0);
        a = *reinterpret_cast<const float4*>(sA + (rg*8+1)*SA + c); FMA4(a,b0,b1,b2,b3,acc1);
        a = *reinterpret_cast<const float4*>(sA + (rg*8+2)*SA + c); FMA4(a,b0,b1,b2,b3,acc2);
        a = *reinterpret_cast<const float4*>(sA + (rg*8+3)*SA + c); FMA4(a,b0,b1,b2,b3,acc3);
        a = *reinterpret_cast<const float4*>(sA + (rg*8+4)*SA + c); FMA4(a,b0,b1,b2,b3,acc4);
        a = *reinterpret_cast<const float4*>(sA + (rg*8+5)*SA + c); FMA4(a,b0,b1,b2,b3,acc5);
        a = *reinterpret_cast<const float4*>(sA + (rg*8+6)*SA + c); FMA4(a,b0,b1,b2,b3,acc6);
        a = *reinterpret_cast<const float4*>(sA + (rg*8+7)*SA + c); FMA4(a,b0,b1,b2,b3,acc7);
    }
    float* op = YwZ + (row0 + rg*8)*128 + d;
    *reinterpret_cast<float4*>(op + 0*128) = acc0;
    *reinterpret_cast<float4*>(op + 1*128) = acc1;
    *reinterpret_cast<float4*>(op + 2*128) = acc2;
    *reinterpret_cast<float4*>(op + 3*128) = acc3;
    *reinterpret_cast<float4*>(op + 4*128) = acc4;
    *reinterpret_cast<float4*>(op + 5*128) = acc5;
    *reinterpret_cast<float4*>(op + 6*128) = acc6;
    *reinterpret_cast<float4*>(op + 7*128) = acc7;
}

// ======================= gather step: v|d = gather(YwZ)/16, relu, out ==========
template<int PINP, int TT, bool LAST>
__global__ __launch_bounds__(256) void gather_kernel(
    const float* __restrict__ xp, const int* __restrict__ idxs,
    const float* __restrict__ yz,      // NPTS x (PINP*128)
    float* __restrict__ Rout,          // NPTS x (TT*64)     [!LAST]
    const float* __restrict__ w4,
    float* __restrict__ hv, float* __restrict__ gpart,   // [LAST]
    int ppb)
{
    constexpr int PCW = PINP * 128;
    constexpr int NSL = PCW / 4;       // 96 / 288 / 864
    constexpr int TC  = TT * 64;
    constexpr int NG  = LAST ? (TC + 255) / 256 : 1;

    __shared__ __align__(16) float buf[TT * 128];   // v at [t][c], d at [t][64+c]
    __shared__ int   sIds[KNB];
    __shared__ float sXg[KNB*3];
    __shared__ float pdt[4][64], pdn[4][64], msc[64];

    const int tid = threadIdx.x;
    const int cpx = gridDim.x >> 3;
    const int eff = (blockIdx.x & 7) * cpx + (blockIdx.x >> 3);

    float gacc[NG];
#pragma unroll
    for (int i = 0; i < NG; ++i) gacc[i] = 0.f;

    const int p0 = eff * ppb;
    for (int pi = 0; pi < ppb; ++pi) {
        const int pt = p0 + pi;
        if (tid < KNB) {
            const int id = idxs[pt*KNB + tid];
            sIds[tid] = id;
            sXg[tid*3+0] = xp[3*id+0];
            sXg[tid*3+1] = xp[3*id+1];
            sXg[tid*3+2] = xp[3*id+2];
        }
        __syncthreads();

        float xr[KNB*3];
#pragma unroll
        for (int e = 0; e < KNB*3; ++e) xr[e] = sXg[e];

        for (int sl = tid; sl < NSL; sl += 256) {
            const int b  = sl >> 5;
            const int cc = (sl & 31) * 4;
            float4 s0 = {0,0,0,0}, s1 = s0, s2 = s0;
#pragma unroll
            for (int k = 0; k < KNB; ++k) {
                const float4 val = *reinterpret_cast<const float4*>(
                    yz + (size_t)sIds[k]*PCW + b*128 + cc);
                const float xa = xr[k*3+0], xb = xr[k*3+1], xc = xr[k*3+2];
                s0.x=fmaf(xa,val.x,s0.x); s0.y=fmaf(xa,val.y,s0.y);
                s0.z=fmaf(xa,val.z,s0.z); s0.w=fmaf(xa,val.w,s0.w);
                s1.x=fmaf(xb,val.x,s1.x); s1.y=fmaf(xb,val.y,s1.y);
                s1.z=fmaf(xb,val.z,s1.z); s1.w=fmaf(xb,val.w,s1.w);
                s2.x=fmaf(xc,val.x,s2.x); s2.y=fmaf(xc,val.y,s2.y);
                s2.z=fmaf(xc,val.z,s2.z); s2.w=fmaf(xc,val.w,s2.w);
            }
            const float inv = 1.0f / KNB;
            s0.x*=inv; s0.y*=inv; s0.z*=inv; s0.w*=inv;
            s1.x*=inv; s1.y*=inv; s1.z*=inv; s1.w*=inv;
            s2.x*=inv; s2.y*=inv; s2.z*=inv; s2.w*=inv;
            *reinterpret_cast<float4*>(buf + (0*PINP + b)*128 + cc) = s0;
            *reinterpret_cast<float4*>(buf + (1*PINP + b)*128 + cc) = s1;
            *reinterpret_cast<float4*>(buf + (2*PINP + b)*128 + cc) = s2;
        }
        __syncthreads();
        {
            const int c = tid & 63, g = tid >> 6;
            float dt = 0.f, dn = 0.f;
            for (int t = g; t < TT; t += 4) {
                const float vv = buf[t*128 + c], dd = buf[t*128 + 64 + c];
                dt = fmaf(vv, dd, dt); dn = fmaf(dd, dd, dn);
            }
            pdt[g][c] = dt; pdn[g][c] = dn;
        }
        __syncthreads();
        if (tid < 64) {
            const float dt = pdt[0][tid]+pdt[1][tid]+pdt[2][tid]+pdt[3][tid];
            const float dn = pdn[0][tid]+pdn[1][tid]+pdn[2][tid]+pdn[3][tid];
            msc[tid] = (dt < 0.f) ? 0.8f * dt / (dn + VEPS) : 0.f;
        }
        __syncthreads();
        if (!LAST) {
            float* op = Rout + (size_t)pt * TC;
            for (int e = tid; e < TC; e += 256) {
                const int t = e >> 6, c = e & 63;
                op[e] = fmaf(-msc[c], buf[t*128 + 64 + c], buf[t*128 + c]);
            }
        } else {
#pragma unroll
            for (int i = 0; i < NG; ++i) {
                const int e = i*256 + tid;
                if (e < TC) {
                    const int t = e >> 6, c = e & 63;
                    const float v = fmaf(-msc[c], buf[t*128 + 64 + c], buf[t*128 + c]);
                    buf[t*128 + c] = v;
                    gacc[i] += v;
                }
            }
            __syncthreads();
            for (int e = tid; e < 9*64; e += 256) {
                const int pq = e >> 6, c = e & 63;
                const int p = pq / 3, qq = pq - 3*p;
                float tr0=0,tr1=0,tr2=0,tr3=0,tr4=0,tr5=0;
#pragma unroll
                for (int r = 0; r < 3; ++r) {
                    tr0 += buf[(r*36 + p*3 + qq )*128 + c];
                    tr1 += buf[(r*30 + p*9 + qq )*128 + c];
                    tr2 += buf[(r*28 + p*9 + qq*3)*128 + c];
                    tr3 += buf[(p*27 + r*12 + qq )*128 + c];
                    tr4 += buf[(p*27 + r*10 + qq*3)*128 + c];
                    tr5 += buf[(p*27 + qq*9 + r*4 )*128 + c];
                }
                const float acc = w4[0*C2 + c]*tr0 + w4[1*C2 + c]*tr1 + w4[2*C2 + c]*tr2
                                + w4[3*C2 + c]*tr3 + w4[4*C2 + c]*tr4 + w4[5*C2 + c]*tr5;
                hv[(size_t)pt * 576 + e] = acc;
            }
        }
        __syncthreads();
    }
    if (LAST) {
#pragma unroll
        for (int i = 0; i < NG; ++i) {
            const int e = i*256 + tid;
            if (e < TC) gpart[(size_t)eff * TC + e] = gacc[i];
        }
    }
}

// ======================= g reduction (1024 parts) =======================
__global__ __launch_bounds__(256) void reduce_g_kernel(const float* __restrict__ gpart,
                                                       float* __restrict__ g)
{
    __shared__ float red[256];
    const int el = threadIdx.x & 15, pg = threadIdx.x >> 4;
    const int e = blockIdx.x * 16 + el;
    float s = 0.f;
    for (int p = pg; p < 1024; p += 16) s += gpart[(size_t)p * (81*C1) + e];
    red[threadIdx.x] = s;
    __syncthreads();
    for (int st = 8; st > 0; st >>= 1) {
        if (pg < st) red[el + 16*pg] += red[el + 16*(pg+st)];
        __syncthreads();
    }
    if (pg == 0) g[e] = red[el] * (1.0f/NPTS);
}

// ======================= hg + hgW precompute =======================
__global__ __launch_bounds__(256) void hgw_kernel(const float* __restrict__ g,
                                                  const float* __restrict__ w4,
                                                  const float* __restrict__ cW,
                                                  float* __restrict__ hgW)
{
    __shared__ float gs[81*C1];
    __shared__ float hg[9*C1];
    const int tid = threadIdx.x;
    for (int e = tid; e < 81*C1; e += 256) gs[e] = g[e];
    __syncthreads();
    for (int e = tid; e < 9*C1; e += 256) {
        const int pq = e >> 6, c = e & 63;
        const int p = pq / 3, qq = pq - 3*p;
        float tr0=0,tr1=0,tr2=0,tr3=0,tr4=0,tr5=0;
#pragma unroll
        for (int r = 0; r < 3; ++r) {
            tr0 += gs[(r*36 + p*3 + qq ) * C1 + c];
            tr1 += gs[(r*30 + p*9 + qq ) * C1 + c];
            tr2 += gs[(r*28 + p*9 + qq*3) * C1 + c];
            tr3 += gs[(p*27 + r*12 + qq ) * C1 + c];
            tr4 += gs[(p*27 + r*10 + qq*3) * C1 + c];
            tr5 += gs[(p*27 + qq*9 + r*4 ) * C1 + c];
        }
        hg[e] = w4[0*C2 + 64 + c]*tr0 + w4[1*C2 + 64 + c]*tr1 + w4[2*C2 + 64 + c]*tr2
              + w4[3*C2 + 64 + c]*tr3 + w4[4*C2 + 64 + c]*tr4 + w4[5*C2 + 64 + c]*tr5;
    }
    __syncthreads();
    for (int o = tid; o < 9*C2; o += 256) {
        const int t = o >> 7, c = o & 127;
        float s = 0.f;
        for (int j = 0; j < C1; ++j) s = fmaf(hg[t*C1 + j], cW[(C1+j)*C2 + c], s);
        hgW[o] = s;
    }
}

// ======================= contraction head =======================
__global__ __launch_bounds__(256) void contract_kernel(const float* __restrict__ hv,
                                                       const float* __restrict__ hgW,
                                                       const float* __restrict__ cW,
                                                       const float* __restrict__ cU,
                                                       const float* __restrict__ w2,
                                                       const int* __restrict__ perm,
                                                       float* __restrict__ out,
                                                       int ppb)
{
    constexpr int S0 = C1 + 4;
    constexpr int SH = C2 + 4;
    __shared__ __align__(16) float h0[36*S0];
    __shared__ __align__(16) float h1[36*SH];
    __shared__ __align__(16) float h2[36*SH];
    __shared__ __align__(16) float hgs[9*C2];
    __shared__ int sPerm[4];

    const int tid = threadIdx.x;
    for (int e = tid; e < 9*C2; e += 256) hgs[e] = hgW[e];
    __syncthreads();

    const int iters = ppb >> 2;
    for (int it = 0; it < iters; ++it) {
        const int base = blockIdx.x * ppb + it * 4;
        if (tid < 4) sPerm[tid] = perm[base + tid];
        for (int e = tid; e < 4*9*C1; e += 256) {
            const int pt = e / 576, rem = e - pt*576;
            const int t = rem >> 6, c = rem & 63;
            h0[(pt*9 + t)*S0 + c] = hv[(size_t)(base+pt)*576 + rem];
        }
        __syncthreads();
        for (int u = tid; u < 9*32; u += 256) {
            const int tg = u >> 5;
            const int d  = (u & 31) * 4;
            const int r0 = tg*4;
            float4 acc0 = *reinterpret_cast<const float4*>(hgs + ((r0+0)%9)*C2 + d);
            float4 acc1 = *reinterpret_cast<const float4*>(hgs + ((r0+1)%9)*C2 + d);
            float4 acc2 = *reinterpret_cast<const float4*>(hgs + ((r0+2)%9)*C2 + d);
            float4 acc3 = *reinterpret_cast<const float4*>(hgs + ((r0+3)%9)*C2 + d);
            for (int c = 0; c < C1; c += 4) {
                const float4 a0 = *reinterpret_cast<const float4*>(h0 + (r0+0)*S0 + c);
                const float4 a1 = *reinterpret_cast<const float4*>(h0 + (r0+1)*S0 + c);
                const float4 a2 = *reinterpret_cast<const float4*>(h0 + (r0+2)*S0 + c);
                const float4 a3 = *reinterpret_cast<const float4*>(h0 + (r0+3)*S0 + c);
                const float4 b0 = *reinterpret_cast<const float4*>(cW + (c+0)*C2 + d);
                const float4 b1 = *reinterpret_cast<const float4*>(cW + (c+1)*C2 + d);
                const float4 b2 = *reinterpret_cast<const float4*>(cW + (c+2)*C2 + d);
                const float4 b3 = *reinterpret_cast<const float4*>(cW + (c+3)*C2 + d);
                FMA4(a0, b0, b1, b2, b3, acc0);
                FMA4(a1, b0, b1, b2, b3, acc1);
                FMA4(a2, b0, b1, b2, b3, acc2);
                FMA4(a3, b0, b1, b2, b3, acc3);
            }
            *reinterpret_cast<float4*>(h1 + (r0+0)*SH + d) = acc0;
            *reinterpret_cast<float4*>(h1 + (r0+1)*SH + d) = acc1;
            *reinterpret_cast<float4*>(h1 + (r0+2)*SH + d) = acc2;
            *reinterpret_cast<float4*>(h1 + (r0+3)*SH + d) = acc3;
        }
        __syncthreads();
        for (int u = tid; u < 9*32; u += 256) {
            const int tg = u >> 5;
            const int d  = (u & 31) * 4;
            const int r0 = tg*4;
            float4 acc0 = {0,0,0,0}, acc1 = acc0, acc2 = acc0, acc3 = acc0;
            for (int c = 0; c < C2; c += 4) {
                const float4 a0 = *reinterpret_cast<const float4*>(h1 + (r0+0)*SH + c);
                const float4 a1 = *reinterpret_cast<const float4*>(h1 + (r0+1)*SH + c);
                const float4 a2 = *reinterpret_cast<const float4*>(h1 + (r0+2)*SH + c);
                const float4 a3 = *reinterpret_cast<const float4*>(h1 + (r0+3)*SH + c);
                const float4 b0 = *reinterpret_cast<const float4*>(cU + (c+0)*C2 + d);
                const float4 b1 = *reinterpret_cast<const float4*>(cU + (c+1)*C2 + d);
                const float4 b2 = *reinterpret_cast<const float4*>(cU + (c+2)*C2 + d);
                const float4 b3 = *reinterpret_cast<const float4*>(cU + (c+3)*C2 + d);
                FMA4(a0, b0, b1, b2, b3, acc0);
                FMA4(a1, b0, b1, b2, b3, acc1);
                FMA4(a2, b0, b1, b2, b3, acc2);
                FMA4(a3, b0, b1, b2, b3, acc3);
            }
            *reinterpret_cast<float4*>(h2 + (r0+0)*SH + d) = acc0;
            *reinterpret_cast<float4*>(h2 + (r0+1)*SH + d) = acc1;
            *reinterpret_cast<float4*>(h2 + (r0+2)*SH + d) = acc2;
            *reinterpret_cast<float4*>(h2 + (r0+3)*SH + d) = acc3;
        }
        __syncthreads();
#pragma unroll
        for (int p2 = 0; p2 < 2; ++p2) {
            const int pair = tid + 256*p2;
            const int pt = pair >> 7, c = pair & 127;
            float dt = 0.f, dn = 0.f;
            for (int t = 0; t < 9; ++t) {
                const float vv = h1[(pt*9+t)*SH + c], dd = h2[(pt*9+t)*SH + c];
                dt = fmaf(vv, dd, dt); dn = fmaf(dd, dd, dn);
            }
            const float m = (dt < 0.f) ? 0.8f * dt / (dn + VEPS) : 0.f;
            float s = 0.f;
#pragma unroll
            for (int r = 0; r < 3; ++r) {
                const int t = r * 4;
                s += fmaf(-m, h2[(pt*9+t)*SH + c], h1[(pt*9+t)*SH + c]);
            }
            out[(size_t)sPerm[pt]*C2 + c] = w2[c] * s;
        }
        __syncthreads();
    }
}

// ======================= launcher =======================
extern "C" void kernel_launch(void* const* d_in, const int* in_sizes, int n_in,
                              void* d_out, int out_size, void* d_ws, size_t ws_size,
                              hipStream_t stream)
{
    (void)in_sizes; (void)n_in; (void)out_size; (void)ws_size;
    const float* x  = (const float*)d_in[0];
    const float* kW = (const float*)d_in[1];
    const float* kU = (const float*)d_in[2];
    const float* w4 = (const float*)d_in[3];
    const float* cW = (const float*)d_in[4];
    const float* cU = (const float*)d_in[5];
    const float* w2 = (const float*)d_in[6];
    float* out = (float*)d_out;

    char* ws = (char*)d_ws;
    size_t off = 0;
    auto alloc = [&](size_t bytes) -> void* {
        void* p = ws + off; off += (bytes + 255) & ~(size_t)255; return p;
    };
    int*   idx   = (int*)  alloc((size_t)NPTS*KNB*4);          // 512 KB
    float* xp    = (float*)alloc((size_t)NPTS*3*4);
    unsigned long long* keys = (unsigned long long*)alloc((size_t)NPTS*8);
    int*   perm  = (int*)  alloc((size_t)NPTS*4);
    float* scol  = (float*)alloc(128*4);
    float* bcat  = (float*)alloc((size_t)3*64*128*4);          // 96 KB
    float* R1    = (float*)alloc((size_t)NPTS*3*C1*4);         // 6.3 MB  (hv aliases here)
    float* YwZ2  = (float*)alloc((size_t)NPTS*3*C2*4);         // 12.6 MB
    float* R2    = (float*)alloc((size_t)NPTS*9*C1*4);         // 18.9 MB (gpart aliases here)
    float* YwZ3  = (float*)alloc((size_t)NPTS*9*C2*4);         // 37.7 MB
    float* R3    = (float*)alloc((size_t)NPTS*27*C1*4);        // 56.6 MB
    float* YwZ4  = (float*)alloc((size_t)NPTS*27*C2*4);        // 113.2 MB (knn parts alias)
    float* g     = (float*)alloc((size_t)81*C1*4);
    float* hgW   = (float*)alloc((size_t)9*C2*4);

    float* hv    = R1;                                 // R1+YwZ2 dead before gather4 writes hv
    float* gpart = R2;                                 // R2+YwZ3 dead before gather4 writes gpart
    unsigned long long* parts = (unsigned long long*)YwZ4;   // dead before zgemm4 writes YwZ4

    keys_kernel<<<NPTS/256, 256, 0, stream>>>(x, keys);
    rank_kernel<<<NPTS/256, 256, 0, stream>>>(keys, x, xp, perm);
    knn_part <<<1024, 256, 0, stream>>>(xp, parts);
    knn_merge<<<NPTS/256, 256, 0, stream>>>(parts, idx);
    prep_kernel<<<4, 256, 0, stream>>>(kW, kU, scol, bcat);
    step1_kernel<<<NPTS/256, 256, 0, stream>>>(xp, idx, scol, R1);

    zgemm_kernel<<<NPTS*3/64,  256, 0, stream>>>(R1, bcat,            YwZ2);
    gather_kernel<3, 9, false><<<1024, 256, 0, stream>>>(xp, idx, YwZ2, R2, nullptr, nullptr, nullptr, 8);
    zgemm_kernel<<<NPTS*9/64,  256, 0, stream>>>(R2, bcat + 8192,     YwZ3);
    gather_kernel<9, 27, false><<<1024, 256, 0, stream>>>(xp, idx, YwZ3, R3, nullptr, nullptr, nullptr, 8);
    zgemm_kernel<<<NPTS*27/64, 256, 0, stream>>>(R3, bcat + 16384,    YwZ4);
    gather_kernel<27, 81, true><<<1024, 256, 0, stream>>>(xp, idx, YwZ4, nullptr, w4, hv, gpart, 8);

    reduce_g_kernel<<<324, 256, 0, stream>>>(gpart, g);
    hgw_kernel<<<1, 256, 0, stream>>>(g, w4, cW, hgW);
    contract_kernel<<<1024, 256, 0, stream>>>(hv, hgW, cW, cU, w2, perm, out, 8);
}

// Round 6
// 869.977 us; speedup vs baseline: 1.2181x; 1.1024x over previous
//
#include <hip/hip_runtime.h>
#include <math.h>

#define NPTS 8192
#define KNB  16
#define C1   64
#define C2   128
#define NEG  0.2f
#define VEPS 1e-6f
#define NCH  32
#define CHSZ (NPTS/NCH)   // 256

// ======================= Morton reorder (exact permutation) =======================
__device__ __forceinline__ unsigned long long expand10(unsigned v) {
    unsigned long long r = v & 0x3FFu;
    r = (r | (r << 16)) & 0x030000FFULL;
    r = (r | (r <<  8)) & 0x0300F00FULL;
    r = (r | (r <<  4)) & 0x030C30C3ULL;
    r = (r | (r <<  2)) & 0x09249249ULL;
    return r;
}

__global__ __launch_bounds__(256) void keys_kernel(const float* __restrict__ x,
                                                   unsigned long long* __restrict__ keys)
{
    const int i = blockIdx.x * 256 + threadIdx.x;
    auto cell = [](float v) -> unsigned {
        float t = (v + 6.f) * (1024.f / 12.f);
        int c = (int)t;
        c = c < 0 ? 0 : (c > 1023 ? 1023 : c);
        return (unsigned)c;
    };
    const unsigned long long m = expand10(cell(x[3*i+0]))
                               | (expand10(cell(x[3*i+1])) << 1)
                               | (expand10(cell(x[3*i+2])) << 2);
    keys[i] = (m << 13) | (unsigned long long)i;
}

__global__ __launch_bounds__(256) void rank_kernel(const unsigned long long* __restrict__ keys,
                                                   const float* __restrict__ x,
                                                   float* __restrict__ xp,
                                                   int* __restrict__ perm)
{
    __shared__ unsigned long long sk[NPTS];
    for (int j = threadIdx.x; j < NPTS; j += 256) sk[j] = keys[j];
    __syncthreads();
    const int i = blockIdx.x * 256 + threadIdx.x;
    const unsigned long long mine = sk[i];
    int r = 0;
    for (int j = 0; j < NPTS; j += 4)
        r += (int)(sk[j] < mine) + (int)(sk[j+1] < mine)
           + (int)(sk[j+2] < mine) + (int)(sk[j+3] < mine);
    perm[r] = i;
    xp[3*r+0] = x[3*i+0]; xp[3*r+1] = x[3*i+1]; xp[3*r+2] = x[3*i+2];
}

// ======================= KNN phase 1: per-chunk top-16 =======================
__global__ __launch_bounds__(256) void knn_part(const float* __restrict__ x,
                                                unsigned long long* __restrict__ parts)
{
    __shared__ __align__(16) float4 cpt[CHSZ];
    __shared__ unsigned long long sbuf[256 * 8];

    const int tid   = threadIdx.x;
    const int chunk = blockIdx.x & (NCH - 1);
    const int qg    = blockIdx.x >> 5;
    const int j0    = chunk * CHSZ;

    cpt[tid] = make_float4(x[3*(j0+tid)+0], x[3*(j0+tid)+1], x[3*(j0+tid)+2], 0.f);
    const int q = qg * 256 + tid;
    const float qx = x[3*q+0], qy = x[3*q+1], qz = x[3*q+2];
    __syncthreads();

    unsigned long long bd[16];
#pragma unroll
    for (int r = 0; r < 16; ++r) bd[r] = ~0ull;
    int cnt = 0;
    unsigned long long* mybuf = sbuf + tid * 8;

    auto flush = [&]() {
#pragma unroll
        for (int s = 0; s < 8; ++s) {
            if (s < cnt) {
                const unsigned long long k = mybuf[s];
                if (k < bd[15]) {
#pragma unroll
                    for (int p2 = 15; p2 > 0; --p2) {
                        const bool sh = k < bd[p2-1];
                        const bool pl = k < bd[p2];
                        bd[p2] = sh ? bd[p2-1] : (pl ? k : bd[p2]);
                    }
                    if (k < bd[0]) bd[0] = k;
                }
            }
        }
        cnt = 0;
    };

    for (int jj = 0; jj < CHSZ; ++jj) {
        const float4 p = cpt[jj];
        const float dx = qx - p.x, dy = qy - p.y, dz = qz - p.z;
        const double ddx = (double)dx, ddy = (double)dy, ddz = (double)dz;
        const double d2 = ddx*ddx + ddy*ddy + ddz*ddz;
        const unsigned long long key =
            (((unsigned long long)__double_as_longlong(d2)) & ~8191ull)
            | (unsigned long long)(j0 + jj);
        if (key < bd[15]) { mybuf[cnt] = key; ++cnt; }
        if (__any(cnt >= 8)) flush();
    }
    flush();

#pragma unroll
    for (int r = 0; r < 16; ++r)
        parts[((size_t)chunk * KNB + r) * NPTS + q] = bd[r];
}

// ======================= KNN phase 2: 32-way sorted merge =======================
__global__ __launch_bounds__(256) void knn_merge(const unsigned long long* __restrict__ parts,
                                                 int* __restrict__ idx_out)
{
    __shared__ unsigned char heads[256][NCH];
    const int tid = threadIdx.x;
    const int q = blockIdx.x * 256 + tid;
    unsigned char* h = heads[tid];
#pragma unroll
    for (int c = 0; c < NCH; ++c) h[c] = 0;
    for (int r = 0; r < KNB; ++r) {
        unsigned long long best = ~0ull; int bc = 0;
#pragma unroll
        for (int c = 0; c < NCH; ++c) {
            const unsigned long long k = parts[((size_t)c * KNB + h[c]) * NPTS + q];
            if (k < best) { best = k; bc = c; }
        }
        h[bc]++;
        idx_out[q*KNB + r] = (int)(best & 8191ull);
    }
}

// ======================= prep: Scol1/ScolU1 + Bcat_t = [W_t | W_t@U_t] ==========
__global__ __launch_bounds__(256) void prep_kernel(const float* __restrict__ kW,
                                                   const float* __restrict__ kU,
                                                   float* __restrict__ scol,
                                                   float* __restrict__ bcat)
{
    __shared__ float sW[64*64];
    __shared__ float sS[64];
    const int t = blockIdx.x;
    const int tid = threadIdx.x;
    if (t == 0) {
        for (int e = tid; e < 64*64; e += 256) sW[e] = kW[e];
        __syncthreads();
        if (tid < 64) {
            float s = 0.f;
            for (int j = 0; j < 64; ++j) s += sW[j*64 + tid];
            sS[tid] = s;
        }
        __syncthreads();
        if (tid < 64) {
            float s2 = 0.f;
            for (int j = 0; j < 64; ++j) s2 = fmaf(sS[j], kU[j*64 + tid], s2);
            scol[tid]      = sS[tid];
            scol[64 + tid] = s2;
        }
    } else {
        const float* W = kW + t*4096;
        const float* U = kU + t*4096;
        for (int e = tid; e < 64*64; e += 256) sW[e] = W[e];
        __syncthreads();
        float* B = bcat + (size_t)(t-1)*64*128;
        for (int o = tid; o < 64*64; o += 256) {
            const int j = o >> 6, c = o & 63;
            float s = 0.f;
            for (int l = 0; l < 64; ++l) s = fmaf(sW[j*64 + l], U[l*64 + c], s);
            B[j*128 + c]      = sW[j*64 + c];
            B[j*128 + 64 + c] = s;
        }
    }
}

// ======================= step1: rank-1 closed form =======================
__global__ __launch_bounds__(256) void step1_kernel(const float* __restrict__ xp,
                                                    const int* __restrict__ idxs,
                                                    const float* __restrict__ scol,
                                                    float* __restrict__ R1)
{
    const int pt = blockIdx.x * 256 + threadIdx.x;
    float mx0 = 0.f, mx1 = 0.f, mx2 = 0.f;
#pragma unroll
    for (int k = 0; k < KNB; ++k) {
        const int id = idxs[pt*KNB + k];
        mx0 += xp[3*id+0]; mx1 += xp[3*id+1]; mx2 += xp[3*id+2];
    }
    const float inv = 1.0f / KNB;
    mx0 *= inv; mx1 *= inv; mx2 *= inv;
    const float S2 = mx0*mx0 + mx1*mx1 + mx2*mx2;
    float* op = R1 + (size_t)pt * 192;
    for (int c = 0; c < 64; ++c) {
        const float sc = scol[c], su = scol[64 + c];
        const float dt = S2 * sc * su;
        const float dn = S2 * su * su;
        const float m  = (dt < 0.f) ? 0.8f * dt / (dn + VEPS) : 0.f;
        const float rc = fmaf(-m, su, sc);
        op[c]       = mx0 * rc;
        op[64 + c]  = mx1 * rc;
        op[128 + c] = mx2 * rc;
    }
}

// ======================= zgemm: YwZ = R @ Bcat (K=64, N=128) =======================
#define FMA4(ar, b0, b1, b2, b3, acc) \
    acc.x = fmaf(ar.x,b0.x, fmaf(ar.y,b1.x, fmaf(ar.z,b2.x, fmaf(ar.w,b3.x, acc.x)))); \
    acc.y = fmaf(ar.x,b0.y, fmaf(ar.y,b1.y, fmaf(ar.z,b2.y, fmaf(ar.w,b3.y, acc.y)))); \
    acc.z = fmaf(ar.x,b0.z, fmaf(ar.y,b1.z, fmaf(ar.z,b2.z, fmaf(ar.w,b3.z, acc.z)))); \
    acc.w = fmaf(ar.x,b0.w, fmaf(ar.y,b1.w, fmaf(ar.z,b2.w, fmaf(ar.w,b3.w, acc.w))));

__global__ __launch_bounds__(256) void zgemm_kernel(const float* __restrict__ R,
                                                    const float* __restrict__ Bcat,
                                                    float* __restrict__ YwZ)
{
    constexpr int SA = 68;
    __shared__ __align__(16) float sA[64*SA];
    __shared__ __align__(16) float sB[64*128];
    const int tid = threadIdx.x;
    const size_t row0 = (size_t)blockIdx.x * 64;

    for (int e4 = tid; e4 < 1024; e4 += 256) {
        const int r = e4 >> 4, c4 = (e4 & 15) * 4;
        *reinterpret_cast<float4*>(sA + r*SA + c4) =
            *reinterpret_cast<const float4*>(R + (row0 + r)*64 + c4);
    }
    for (int e4 = tid; e4 < 2048; e4 += 256) {
        const int j = e4 >> 5, c4 = (e4 & 31) * 4;
        *reinterpret_cast<float4*>(sB + j*128 + c4) =
            *reinterpret_cast<const float4*>(Bcat + j*128 + c4);
    }
    __syncthreads();

    const int rg = tid >> 5;
    const int d  = (tid & 31) * 4;
    float4 acc0={0,0,0,0},acc1=acc0,acc2=acc0,acc3=acc0,acc4=acc0,acc5=acc0,acc6=acc0,acc7=acc0;
    for (int c = 0; c < 64; c += 4) {
        const float4 b0 = *reinterpret_cast<const float4*>(sB + (c+0)*128 + d);
        const float4 b1 = *reinterpret_cast<const float4*>(sB + (c+1)*128 + d);
        const float4 b2 = *reinterpret_cast<const float4*>(sB + (c+2)*128 + d);
        const float4 b3 = *reinterpret_cast<const float4*>(sB + (c+3)*128 + d);
        float4 a;
        a = *reinterpret_cast<const float4*>(sA + (rg*8+0)*SA + c); FMA4(a,b0,b1,b2,b3,acc0);
        a = *reinterpret_cast<const float4*>(sA + (rg*8+1)*SA + c); FMA4(a,b0,b1,b2,b3,acc1);
        a = *reinterpret_cast<const float4*>(sA + (rg*8+2)*SA + c); FMA4(a,b0,b1,b2,b3,acc2);
        a = *reinterpret_cast<const float4*>(sA + (rg*8+3)*SA + c); FMA4(a,b0,b1,b2,b3,acc3);
        a = *reinterpret_cast<const float4*>(sA + (rg*8+4)*SA + c); FMA4(a,b0,b1,b2,b3,acc4);
        a = *reinterpret_cast<const float4*>(sA + (rg*8+5)*SA + c); FMA4(a,b0,b1,b2,b3,acc5);
        a = *reinterpret_cast<const float4*>(sA + (rg*8+6)*SA + c); FMA4(a,b0,b1,b2,b3,acc6);
        a = *reinterpret_cast<const float4*>(sA + (rg*8+7)*SA + c); FMA4(a,b0,b1,b2,b3,acc7);
    }
    float* op = YwZ + (row0 + rg*8)*128 + d;
    *reinterpret_cast<float4*>(op + 0*128) = acc0;
    *reinterpret_cast<float4*>(op + 1*128) = acc1;
    *reinterpret_cast<float4*>(op + 2*128) = acc2;
    *reinterpret_cast<float4*>(op + 3*128) = acc3;
    *reinterpret_cast<float4*>(op + 4*128) = acc4;
    *reinterpret_cast<float4*>(op + 5*128) = acc5;
    *reinterpret_cast<float4*>(op + 6*128) = acc6;
    *reinterpret_cast<float4*>(op + 7*128) = acc7;
}

// ======================= gather step: v|d = gather(YwZ)/16, relu, out ==========
// Sliding-window point striping: all blocks of an XCD process the SAME ~128-pt
// Morton window concurrently (pt = xcd*1024 + pi*slots + slot), so the
// neighbor-row working set (~2-3 MB) stays resident in the 4MB XCD L2.
template<int PINP, int TT, bool LAST>
__global__ __launch_bounds__(256) void gather_kernel(
    const float* __restrict__ xp, const int* __restrict__ idxs,
    const float* __restrict__ yz,
    float* __restrict__ Rout,
    const float* __restrict__ w4,
    float* __restrict__ hv, float* __restrict__ gpart,
    int ppb)
{
    constexpr int PCW = PINP * 128;
    constexpr int NSL = PCW / 4;
    constexpr int TC  = TT * 64;
    constexpr int NG  = LAST ? (TC + 255) / 256 : 1;

    __shared__ __align__(16) float buf[TT * 128];
    __shared__ int   sIds[KNB];
    __shared__ float sXg[KNB*3];
    __shared__ float pdt[4][64], pdn[4][64], msc[64];

    const int tid   = threadIdx.x;
    const int slots = gridDim.x >> 3;           // blocks per XCD
    const int xcd   = blockIdx.x & 7;
    const int slot  = blockIdx.x >> 3;
    const int eff   = xcd * slots + slot;       // gpart slot
    const int base  = xcd * slots * ppb;

    float gacc[NG];
#pragma unroll
    for (int i = 0; i < NG; ++i) gacc[i] = 0.f;

    for (int pi = 0; pi < ppb; ++pi) {
        const int pt = base + pi * slots + slot;
        if (tid < KNB) {
            const int id = idxs[pt*KNB + tid];
            sIds[tid] = id;
            sXg[tid*3+0] = xp[3*id+0];
            sXg[tid*3+1] = xp[3*id+1];
            sXg[tid*3+2] = xp[3*id+2];
        }
        __syncthreads();

        float xr[KNB*3];
#pragma unroll
        for (int e = 0; e < KNB*3; ++e) xr[e] = sXg[e];

        for (int sl = tid; sl < NSL; sl += 256) {
            const int b  = sl >> 5;
            const int cc = (sl & 31) * 4;
            float4 s0 = {0,0,0,0}, s1 = s0, s2 = s0;
#pragma unroll
            for (int k = 0; k < KNB; ++k) {
                const float4 val = *reinterpret_cast<const float4*>(
                    yz + (size_t)sIds[k]*PCW + b*128 + cc);
                const float xa = xr[k*3+0], xb = xr[k*3+1], xc = xr[k*3+2];
                s0.x=fmaf(xa,val.x,s0.x); s0.y=fmaf(xa,val.y,s0.y);
                s0.z=fmaf(xa,val.z,s0.z); s0.w=fmaf(xa,val.w,s0.w);
                s1.x=fmaf(xb,val.x,s1.x); s1.y=fmaf(xb,val.y,s1.y);
                s1.z=fmaf(xb,val.z,s1.z); s1.w=fmaf(xb,val.w,s1.w);
                s2.x=fmaf(xc,val.x,s2.x); s2.y=fmaf(xc,val.y,s2.y);
                s2.z=fmaf(xc,val.z,s2.z); s2.w=fmaf(xc,val.w,s2.w);
            }
            const float inv = 1.0f / KNB;
            s0.x*=inv; s0.y*=inv; s0.z*=inv; s0.w*=inv;
            s1.x*=inv; s1.y*=inv; s1.z*=inv; s1.w*=inv;
            s2.x*=inv; s2.y*=inv; s2.z*=inv; s2.w*=inv;
            *reinterpret_cast<float4*>(buf + (0*PINP + b)*128 + cc) = s0;
            *reinterpret_cast<float4*>(buf + (1*PINP + b)*128 + cc) = s1;
            *reinterpret_cast<float4*>(buf + (2*PINP + b)*128 + cc) = s2;
        }
        __syncthreads();
        {
            const int c = tid & 63, g = tid >> 6;
            float dt = 0.f, dn = 0.f;
            for (int t = g; t < TT; t += 4) {
                const float vv = buf[t*128 + c], dd = buf[t*128 + 64 + c];
                dt = fmaf(vv, dd, dt); dn = fmaf(dd, dd, dn);
            }
            pdt[g][c] = dt; pdn[g][c] = dn;
        }
        __syncthreads();
        if (tid < 64) {
            const float dt = pdt[0][tid]+pdt[1][tid]+pdt[2][tid]+pdt[3][tid];
            const float dn = pdn[0][tid]+pdn[1][tid]+pdn[2][tid]+pdn[3][tid];
            msc[tid] = (dt < 0.f) ? 0.8f * dt / (dn + VEPS) : 0.f;
        }
        __syncthreads();
        if (!LAST) {
            float* op = Rout + (size_t)pt * TC;
            for (int e = tid; e < TC; e += 256) {
                const int t = e >> 6, c = e & 63;
                op[e] = fmaf(-msc[c], buf[t*128 + 64 + c], buf[t*128 + c]);
            }
        } else {
#pragma unroll
            for (int i = 0; i < NG; ++i) {
                const int e = i*256 + tid;
                if (e < TC) {
                    const int t = e >> 6, c = e & 63;
                    const float v = fmaf(-msc[c], buf[t*128 + 64 + c], buf[t*128 + c]);
                    buf[t*128 + c] = v;
                    gacc[i] += v;
                }
            }
            __syncthreads();
            for (int e = tid; e < 9*64; e += 256) {
                const int pq = e >> 6, c = e & 63;
                const int p = pq / 3, qq = pq - 3*p;
                float tr0=0,tr1=0,tr2=0,tr3=0,tr4=0,tr5=0;
#pragma unroll
                for (int r = 0; r < 3; ++r) {
                    tr0 += buf[(r*36 + p*3 + qq )*128 + c];
                    tr1 += buf[(r*30 + p*9 + qq )*128 + c];
                    tr2 += buf[(r*28 + p*9 + qq*3)*128 + c];
                    tr3 += buf[(p*27 + r*12 + qq )*128 + c];
                    tr4 += buf[(p*27 + r*10 + qq*3)*128 + c];
                    tr5 += buf[(p*27 + qq*9 + r*4 )*128 + c];
                }
                const float acc = w4[0*C2 + c]*tr0 + w4[1*C2 + c]*tr1 + w4[2*C2 + c]*tr2
                                + w4[3*C2 + c]*tr3 + w4[4*C2 + c]*tr4 + w4[5*C2 + c]*tr5;
                hv[(size_t)pt * 576 + e] = acc;
            }
        }
        __syncthreads();
    }
    if (LAST) {
#pragma unroll
        for (int i = 0; i < NG; ++i) {
            const int e = i*256 + tid;
            if (e < TC) gpart[(size_t)eff * TC + e] = gacc[i];
        }
    }
}

// ======================= g reduction (1024 parts) =======================
__global__ __launch_bounds__(256) void reduce_g_kernel(const float* __restrict__ gpart,
                                                       float* __restrict__ g)
{
    __shared__ float red[256];
    const int el = threadIdx.x & 15, pg = threadIdx.x >> 4;
    const int e = blockIdx.x * 16 + el;
    float s = 0.f;
    for (int p = pg; p < 1024; p += 16) s += gpart[(size_t)p * (81*C1) + e];
    red[threadIdx.x] = s;
    __syncthreads();
    for (int st = 8; st > 0; st >>= 1) {
        if (pg < st) red[el + 16*pg] += red[el + 16*(pg+st)];
        __syncthreads();
    }
    if (pg == 0) g[e] = red[el] * (1.0f/NPTS);
}

// ======================= hg + hgW precompute =======================
__global__ __launch_bounds__(256) void hgw_kernel(const float* __restrict__ g,
                                                  const float* __restrict__ w4,
                                                  const float* __restrict__ cW,
                                                  float* __restrict__ hgW)
{
    __shared__ float gs[81*C1];
    __shared__ float hg[9*C1];
    const int tid = threadIdx.x;
    for (int e = tid; e < 81*C1; e += 256) gs[e] = g[e];
    __syncthreads();
    for (int e = tid; e < 9*C1; e += 256) {
        const int pq = e >> 6, c = e & 63;
        const int p = pq / 3, qq = pq - 3*p;
        float tr0=0,tr1=0,tr2=0,tr3=0,tr4=0,tr5=0;
#pragma unroll
        for (int r = 0; r < 3; ++r) {
            tr0 += gs[(r*36 + p*3 + qq ) * C1 + c];
            tr1 += gs[(r*30 + p*9 + qq ) * C1 + c];
            tr2 += gs[(r*28 + p*9 + qq*3) * C1 + c];
            tr3 += gs[(p*27 + r*12 + qq ) * C1 + c];
            tr4 += gs[(p*27 + r*10 + qq*3) * C1 + c];
            tr5 += gs[(p*27 + qq*9 + r*4 ) * C1 + c];
        }
        hg[e] = w4[0*C2 + 64 + c]*tr0 + w4[1*C2 + 64 + c]*tr1 + w4[2*C2 + 64 + c]*tr2
              + w4[3*C2 + 64 + c]*tr3 + w4[4*C2 + 64 + c]*tr4 + w4[5*C2 + 64 + c]*tr5;
    }
    __syncthreads();
    for (int o = tid; o < 9*C2; o += 256) {
        const int t = o >> 7, c = o & 127;
        float s = 0.f;
        for (int j = 0; j < C1; ++j) s = fmaf(hg[t*C1 + j], cW[(C1+j)*C2 + c], s);
        hgW[o] = s;
    }
}

// ======================= contraction head =======================
__global__ __launch_bounds__(256) void contract_kernel(const float* __restrict__ hv,
                                                       const float* __restrict__ hgW,
                                                       const float* __restrict__ cW,
                                                       const float* __restrict__ cU,
                                                       const float* __restrict__ w2,
                                                       const int* __restrict__ perm,
                                                       float* __restrict__ out,
                                                       int ppb)
{
    constexpr int S0 = C1 + 4;
    constexpr int SH = C2 + 4;
    __shared__ __align__(16) float h0[36*S0];
    __shared__ __align__(16) float h1[36*SH];
    __shared__ __align__(16) float h2[36*SH];
    __shared__ __align__(16) float hgs[9*C2];
    __shared__ int sPerm[4];

    const int tid = threadIdx.x;
    for (int e = tid; e < 9*C2; e += 256) hgs[e] = hgW[e];
    __syncthreads();

    const int iters = ppb >> 2;
    for (int it = 0; it < iters; ++it) {
        const int base = blockIdx.x * ppb + it * 4;
        if (tid < 4) sPerm[tid] = perm[base + tid];
        for (int e = tid; e < 4*9*C1; e += 256) {
            const int pt = e / 576, rem = e - pt*576;
            const int t = rem >> 6, c = rem & 63;
            h0[(pt*9 + t)*S0 + c] = hv[(size_t)(base+pt)*576 + rem];
        }
        __syncthreads();
        for (int u = tid; u < 9*32; u += 256) {
            const int tg = u >> 5;
            const int d  = (u & 31) * 4;
            const int r0 = tg*4;
            float4 acc0 = *reinterpret_cast<const float4*>(hgs + ((r0+0)%9)*C2 + d);
            float4 acc1 = *reinterpret_cast<const float4*>(hgs + ((r0+1)%9)*C2 + d);
            float4 acc2 = *reinterpret_cast<const float4*>(hgs + ((r0+2)%9)*C2 + d);
            float4 acc3 = *reinterpret_cast<const float4*>(hgs + ((r0+3)%9)*C2 + d);
            for (int c = 0; c < C1; c += 4) {
                const float4 a0 = *reinterpret_cast<const float4*>(h0 + (r0+0)*S0 + c);
                const float4 a1 = *reinterpret_cast<const float4*>(h0 + (r0+1)*S0 + c);
                const float4 a2 = *reinterpret_cast<const float4*>(h0 + (r0+2)*S0 + c);
                const float4 a3 = *reinterpret_cast<const float4*>(h0 + (r0+3)*S0 + c);
                const float4 b0 = *reinterpret_cast<const float4*>(cW + (c+0)*C2 + d);
                const float4 b1 = *reinterpret_cast<const float4*>(cW + (c+1)*C2 + d);
                const float4 b2 = *reinterpret_cast<const float4*>(cW + (c+2)*C2 + d);
                const float4 b3 = *reinterpret_cast<const float4*>(cW + (c+3)*C2 + d);
                FMA4(a0, b0, b1, b2, b3, acc0);
                FMA4(a1, b0, b1, b2, b3, acc1);
                FMA4(a2, b0, b1, b2, b3, acc2);
                FMA4(a3, b0, b1, b2, b3, acc3);
            }
            *reinterpret_cast<float4*>(h1 + (r0+0)*SH + d) = acc0;
            *reinterpret_cast<float4*>(h1 + (r0+1)*SH + d) = acc1;
            *reinterpret_cast<float4*>(h1 + (r0+2)*SH + d) = acc2;
            *reinterpret_cast<float4*>(h1 + (r0+3)*SH + d) = acc3;
        }
        __syncthreads();
        for (int u = tid; u < 9*32; u += 256) {
            const int tg = u >> 5;
            const int d  = (u & 31) * 4;
            const int r0 = tg*4;
            float4 acc0 = {0,0,0,0}, acc1 = acc0, acc2 = acc0, acc3 = acc0;
            for (int c = 0; c < C2; c += 4) {
                const float4 a0 = *reinterpret_cast<const float4*>(h1 + (r0+0)*SH + c);
                const float4 a1 = *reinterpret_cast<const float4*>(h1 + (r0+1)*SH + c);
                const float4 a2 = *reinterpret_cast<const float4*>(h1 + (r0+2)*SH + c);
                const float4 a3 = *reinterpret_cast<const float4*>(h1 + (r0+3)*SH + c);
                const float4 b0 = *reinterpret_cast<const float4*>(cU + (c+0)*C2 + d);
                const float4 b1 = *reinterpret_cast<const float4*>(cU + (c+1)*C2 + d);
                const float4 b2 = *reinterpret_cast<const float4*>(cU + (c+2)*C2 + d);
                const float4 b3 = *reinterpret_cast<const float4*>(cU + (c+3)*C2 + d);
                FMA4(a0, b0, b1, b2, b3, acc0);
                FMA4(a1, b0, b1, b2, b3, acc1);
                FMA4(a2, b0, b1, b2, b3, acc2);
                FMA4(a3, b0, b1, b2, b3, acc3);
            }
            *reinterpret_cast<float4*>(h2 + (r0+0)*SH + d) = acc0;
            *reinterpret_cast<float4*>(h2 + (r0+1)*SH + d) = acc1;
            *reinterpret_cast<float4*>(h2 + (r0+2)*SH + d) = acc2;
            *reinterpret_cast<float4*>(h2 + (r0+3)*SH + d) = acc3;
        }
        __syncthreads();
#pragma unroll
        for (int p2 = 0; p2 < 2; ++p2) {
            const int pair = tid + 256*p2;
            const int pt = pair >> 7, c = pair & 127;
            float dt = 0.f, dn = 0.f;
            for (int t = 0; t < 9; ++t) {
                const float vv = h1[(pt*9+t)*SH + c], dd = h2[(pt*9+t)*SH + c];
                dt = fmaf(vv, dd, dt); dn = fmaf(dd, dd, dn);
            }
            const float m = (dt < 0.f) ? 0.8f * dt / (dn + VEPS) : 0.f;
            float s = 0.f;
#pragma unroll
            for (int r = 0; r < 3; ++r) {
                const int t = r * 4;
                s += fmaf(-m, h2[(pt*9+t)*SH + c], h1[(pt*9+t)*SH + c]);
            }
            out[(size_t)sPerm[pt]*C2 + c] = w2[c] * s;
        }
        __syncthreads();
    }
}

// ======================= launcher =======================
extern "C" void kernel_launch(void* const* d_in, const int* in_sizes, int n_in,
                              void* d_out, int out_size, void* d_ws, size_t ws_size,
                              hipStream_t stream)
{
    (void)in_sizes; (void)n_in; (void)out_size; (void)ws_size;
    const float* x  = (const float*)d_in[0];
    const float* kW = (const float*)d_in[1];
    const float* kU = (const float*)d_in[2];
    const float* w4 = (const float*)d_in[3];
    const float* cW = (const float*)d_in[4];
    const float* cU = (const float*)d_in[5];
    const float* w2 = (const float*)d_in[6];
    float* out = (float*)d_out;

    char* ws = (char*)d_ws;
    size_t off = 0;
    auto alloc = [&](size_t bytes) -> void* {
        void* p = ws + off; off += (bytes + 255) & ~(size_t)255; return p;
    };
    int*   idx   = (int*)  alloc((size_t)NPTS*KNB*4);
    float* xp    = (float*)alloc((size_t)NPTS*3*4);
    unsigned long long* keys = (unsigned long long*)alloc((size_t)NPTS*8);
    int*   perm  = (int*)  alloc((size_t)NPTS*4);
    float* scol  = (float*)alloc(128*4);
    float* bcat  = (float*)alloc((size_t)3*64*128*4);
    float* R1    = (float*)alloc((size_t)NPTS*3*C1*4);
    float* YwZ2  = (float*)alloc((size_t)NPTS*3*C2*4);
    float* R2    = (float*)alloc((size_t)NPTS*9*C1*4);
    float* YwZ3  = (float*)alloc((size_t)NPTS*9*C2*4);
    float* R3    = (float*)alloc((size_t)NPTS*27*C1*4);
    float* YwZ4  = (float*)alloc((size_t)NPTS*27*C2*4);
    float* g     = (float*)alloc((size_t)81*C1*4);
    float* hgW   = (float*)alloc((size_t)9*C2*4);

    float* hv    = R1;
    float* gpart = R2;
    unsigned long long* parts = (unsigned long long*)YwZ4;

    keys_kernel<<<NPTS/256, 256, 0, stream>>>(x, keys);
    rank_kernel<<<NPTS/256, 256, 0, stream>>>(keys, x, xp, perm);
    knn_part <<<1024, 256, 0, stream>>>(xp, parts);
    knn_merge<<<NPTS/256, 256, 0, stream>>>(parts, idx);
    prep_kernel<<<4, 256, 0, stream>>>(kW, kU, scol, bcat);
    step1_kernel<<<NPTS/256, 256, 0, stream>>>(xp, idx, scol, R1);

    zgemm_kernel<<<NPTS*3/64,  256, 0, stream>>>(R1, bcat,            YwZ2);
    gather_kernel<3, 9, false><<<1024, 256, 0, stream>>>(xp, idx, YwZ2, R2, nullptr, nullptr, nullptr, 8);
    zgemm_kernel<<<NPTS*9/64,  256, 0, stream>>>(R2, bcat + 8192,     YwZ3);
    gather_kernel<9, 27, false><<<1024, 256, 0, stream>>>(xp, idx, YwZ3, R3, nullptr, nullptr, nullptr, 8);
    zgemm_kernel<<<NPTS*27/64, 256, 0, stream>>>(R3, bcat + 16384,    YwZ4);
    gather_kernel<27, 81, true><<<1024, 256, 0, stream>>>(xp, idx, YwZ4, nullptr, w4, hv, gpart, 8);

    reduce_g_kernel<<<324, 256, 0, stream>>>(gpart, g);
    hgw_kernel<<<1, 256, 0, stream>>>(g, w4, cW, hgW);
    contract_kernel<<<1024, 256, 0, stream>>>(hv, hgW, cW, cU, w2, perm, out, 8);
}